// Round 6
// baseline (118.270 us; speedup 1.0000x reference)
//
#include <hip/hip_runtime.h>
#include <hip/hip_bf16.h>
#include <stdint.h>

// Problem constants: B=2, T=2048, D=1024, H=16, W=256, HD=64; M = B*T = 4096.

typedef __attribute__((ext_vector_type(8))) short short8;
typedef __attribute__((ext_vector_type(4))) float f32x4;

#define MFMA16(a, b, c) __builtin_amdgcn_mfma_f32_16x16x32_bf16((a), (b), (c), 0, 0, 0)

static __device__ __forceinline__ void gl_lds16(const void* g, void* l) {
  __builtin_amdgcn_global_load_lds(
      (const __attribute__((address_space(1))) unsigned int*)g,
      (__attribute__((address_space(3))) unsigned int*)l, 16, 0, 0);
}

#define LGKM0 do { asm volatile("s_waitcnt lgkmcnt(0)" ::: "memory"); \
                   __builtin_amdgcn_sched_barrier(0); } while (0)
#define BARM do { asm volatile("" ::: "memory"); \
                  __builtin_amdgcn_s_barrier(); \
                  asm volatile("" ::: "memory"); } while (0)

// ---------------------------------------------------------------- convert all
__global__ void cvt_all(const float* __restrict__ x, const float* __restrict__ wqkv,
                        const float* __restrict__ wo, __hip_bfloat16* __restrict__ xb,
                        __hip_bfloat16* __restrict__ wqkvb,
                        __hip_bfloat16* __restrict__ wob) {
  const int N0 = 524288, N1 = 393216, N2 = 131072;  // granules of 8 floats
  int i = blockIdx.x * blockDim.x + threadIdx.x;
  const int stride = gridDim.x * blockDim.x;
  for (; i < N0 + N1 + N2; i += stride) {
    const float* in;
    __hip_bfloat16* out;
    int gidx;
    if (i < N0) { in = x; out = xb; gidx = i; }
    else if (i < N0 + N1) { in = wqkv; out = wqkvb; gidx = i - N0; }
    else { in = wo; out = wob; gidx = i - N0 - N1; }
    const float4* p = (const float4*)in + (size_t)gidx * 2;
    float4 v0 = p[0], v1 = p[1];
    union { short8 s; __hip_bfloat16 h[8]; } u;
    u.h[0] = __float2bfloat16(v0.x); u.h[1] = __float2bfloat16(v0.y);
    u.h[2] = __float2bfloat16(v0.z); u.h[3] = __float2bfloat16(v0.w);
    u.h[4] = __float2bfloat16(v1.x); u.h[5] = __float2bfloat16(v1.y);
    u.h[6] = __float2bfloat16(v1.z); u.h[7] = __float2bfloat16(v1.w);
    ((short8*)out)[gidx] = u.s;
  }
}

// ---------------------------------------------------------------- QKV GEMM
// (unchanged from round 3)
__global__ __launch_bounds__(512) void gemm_qkv(
    const __hip_bfloat16* __restrict__ A, const __hip_bfloat16* __restrict__ Bm,
    const float* __restrict__ bias,
    __hip_bfloat16* __restrict__ qb, __hip_bfloat16* __restrict__ kb,
    __hip_bfloat16* __restrict__ vt) {
  __shared__ alignas(128) char smem[114688];
  const int tid = threadIdx.x;
  const int lane = tid & 63, w = tid >> 6;
  const int wm = w >> 2, wn = w & 3;
  const int r = lane & 15, g = lane >> 4;
  const int K = 1024, NT = 16;

  const int cpx = gridDim.x >> 3;
  const int swzb = (blockIdx.x & 7) * cpx + (blockIdx.x >> 3);
  const int bm = swzb >> 4, bn = swzb & 15;

  const int srow = tid >> 3;
  const int e = (tid & 7) ^ ((tid >> 4) & 7);
  const int koff = (e >> 2) * 32 + (e & 3) * 8;
  const __hip_bfloat16* aU[4];
  const __hip_bfloat16* bU[3];
#pragma unroll
  for (int U = 0; U < 4; ++U)
    aU[U] = A + (size_t)(bm * 256 + U * 64 + srow) * K + koff;
#pragma unroll
  for (int U = 0; U < 3; ++U)
    bU[U] = Bm + (size_t)(bn * 192 + U * 64 + srow) * K + koff;
  const int ldst = tid * 16;

#define STA(t, U) gl_lds16(aU[U] + (t) * 64, smem + ((t) & 1) * 57344 + (U) * 8192 + ldst)
#define STB(t, U) gl_lds16(bU[U] + (t) * 64, smem + ((t) & 1) * 57344 + 32768 + (U) * 8192 + ldst)

  const int hsw = (r >> 1) & 7;
  const int s0 = ((0 + g) ^ hsw) * 16;
  const int s1 = ((4 + g) ^ hsw) * 16;
  const int rdA = (wm * 128 + r) * 128;
  const int rdB = 32768 + (wn * 48 + r) * 128;

  f32x4 acc[8][3] = {};
  short8 a0[4][2], a1[4][2], bb[3][2];

#pragma unroll
  for (int U = 0; U < 4; ++U) STA(0, U);
#pragma unroll
  for (int U = 0; U < 3; ++U) STB(0, U);
#pragma unroll
  for (int U = 0; U < 4; ++U) STA(1, U);
#pragma unroll
  for (int U = 0; U < 3; ++U) STB(1, U);
  asm volatile("s_waitcnt vmcnt(7)" ::: "memory");
  BARM;

#pragma unroll 1
  for (int t = 0; t < NT; ++t) {
    const char* cb = smem + (t & 1) * 57344;
#pragma unroll
    for (int i = 0; i < 4; ++i) {
      a0[i][0] = *(const short8*)(cb + rdA + i * 2048 + s0);
      a0[i][1] = *(const short8*)(cb + rdA + i * 2048 + s1);
    }
#pragma unroll
    for (int j = 0; j < 2; ++j) {
      bb[j][0] = *(const short8*)(cb + rdB + j * 2048 + s0);
      bb[j][1] = *(const short8*)(cb + rdB + j * 2048 + s1);
    }
    BARM;
    LGKM0;
    __builtin_amdgcn_s_setprio(1);
#pragma unroll
    for (int i = 0; i < 4; ++i)
#pragma unroll
      for (int j = 0; j < 2; ++j) acc[i][j] = MFMA16(a0[i][0], bb[j][0], acc[i][j]);
#pragma unroll
    for (int i = 0; i < 4; ++i)
#pragma unroll
      for (int j = 0; j < 2; ++j) acc[i][j] = MFMA16(a0[i][1], bb[j][1], acc[i][j]);
    __builtin_amdgcn_s_setprio(0);
    BARM;
#pragma unroll
    for (int i = 0; i < 4; ++i) {
      a1[i][0] = *(const short8*)(cb + rdA + (i + 4) * 2048 + s0);
      a1[i][1] = *(const short8*)(cb + rdA + (i + 4) * 2048 + s1);
    }
    BARM;
    LGKM0;
    __builtin_amdgcn_s_setprio(1);
#pragma unroll
    for (int i = 0; i < 4; ++i)
#pragma unroll
      for (int j = 0; j < 2; ++j) acc[i + 4][j] = MFMA16(a1[i][0], bb[j][0], acc[i + 4][j]);
#pragma unroll
    for (int i = 0; i < 4; ++i)
#pragma unroll
      for (int j = 0; j < 2; ++j) acc[i + 4][j] = MFMA16(a1[i][1], bb[j][1], acc[i + 4][j]);
    __builtin_amdgcn_s_setprio(0);
    BARM;
    bb[2][0] = *(const short8*)(cb + rdB + 2 * 2048 + s0);
    bb[2][1] = *(const short8*)(cb + rdB + 2 * 2048 + s1);
    if (t + 2 < NT) {
      STA(t + 2, 0); STA(t + 2, 1); STA(t + 2, 2); STA(t + 2, 3);
    }
    BARM;
    LGKM0;
    __builtin_amdgcn_s_setprio(1);
#pragma unroll
    for (int i = 0; i < 4; ++i) acc[i + 4][2] = MFMA16(a1[i][0], bb[2][0], acc[i + 4][2]);
#pragma unroll
    for (int i = 0; i < 4; ++i) acc[i + 4][2] = MFMA16(a1[i][1], bb[2][1], acc[i + 4][2]);
    __builtin_amdgcn_s_setprio(0);
    BARM;
    if (t + 2 < NT) {
      STB(t + 2, 0); STB(t + 2, 1); STB(t + 2, 2);
    }
    BARM;
    __builtin_amdgcn_s_setprio(1);
#pragma unroll
    for (int i = 0; i < 4; ++i) acc[i][2] = MFMA16(a0[i][0], bb[2][0], acc[i][2]);
#pragma unroll
    for (int i = 0; i < 4; ++i) acc[i][2] = MFMA16(a0[i][1], bb[2][1], acc[i][2]);
    __builtin_amdgcn_s_setprio(0);
    if (t + 2 < NT) {
      asm volatile("s_waitcnt vmcnt(7)" ::: "memory");
    } else if (t + 1 < NT) {
      asm volatile("s_waitcnt vmcnt(0)" ::: "memory");
    }
    BARM;
  }
#undef STA
#undef STB

  float bjv[3];
  const int nb = bn * 192 + wn * 48;
#pragma unroll
  for (int j = 0; j < 3; ++j) bjv[j] = bias[nb + j * 16 + r];
#pragma unroll
  for (int i = 0; i < 8; ++i) {
    const int m0 = bm * 256 + wm * 128 + i * 16 + g * 4;
#pragma unroll
    for (int j = 0; j < 3; ++j) {
      const int nn = nb + j * 16 + r;
      const int c = nn >> 10, h = (nn >> 6) & 15, hd = nn & 63;
      const int b_ = m0 >> 11, t0 = m0 & 2047;
      const size_t hb = (size_t)(b_ * 16 + h);
      if (c == 0) {
#pragma unroll
        for (int q = 0; q < 4; ++q)
          qb[(hb * 2048 + t0 + q) * 64 + hd] =
              __float2bfloat16((acc[i][j][q] + bjv[j]) * 0.125f);
      } else if (c == 1) {
#pragma unroll
        for (int q = 0; q < 4; ++q)
          kb[(hb * 2048 + t0 + q) * 64 + hd] =
              __float2bfloat16(acc[i][j][q] + bjv[j]);
      } else {
        union { uint2 u; __hip_bfloat16 hh[4]; } pk;
#pragma unroll
        for (int q = 0; q < 4; ++q)
          pk.hh[q] = __float2bfloat16(acc[i][j][q] + bjv[j]);
        *(uint2*)&vt[(hb * 64 + hd) * 2048 + t0] = pk.u;
      }
    }
  }
}

// ---------------------------------------------------------------- 128x128 GEMM
// (out-projection, unchanged)
__global__ __launch_bounds__(256) void gemm_bt_out(
    const __hip_bfloat16* __restrict__ A, const __hip_bfloat16* __restrict__ Bm,
    const float* __restrict__ bias, float* __restrict__ outF, int K, int nbn) {
  __shared__ alignas(16) __hip_bfloat16 As[128 * 32];
  __shared__ alignas(16) __hip_bfloat16 Bs[128 * 32];
  const int bm = blockIdx.x / nbn, bn = blockIdx.x % nbn;
  const int tid = threadIdx.x;
  const int lane = tid & 63, w = tid >> 6;
  const int wr = w >> 1, wc = w & 1;
  const int r = lane & 15, g = lane >> 4;

  f32x4 acc[4][4] = {};

  const int c0 = tid, c1 = tid + 256;
  const __hip_bfloat16* a0 = A + (size_t)(bm * 128 + (c0 >> 2)) * K + (c0 & 3) * 8;
  const __hip_bfloat16* a1 = A + (size_t)(bm * 128 + (c1 >> 2)) * K + (c1 & 3) * 8;
  const __hip_bfloat16* b0 = Bm + (size_t)(bn * 128 + (c0 >> 2)) * K + (c0 & 3) * 8;
  const __hip_bfloat16* b1 = Bm + (size_t)(bn * 128 + (c1 >> 2)) * K + (c1 & 3) * 8;
  __hip_bfloat16* la0 = &As[c0 * 8];
  __hip_bfloat16* la1 = &As[c1 * 8];
  __hip_bfloat16* lb0 = &Bs[c0 * 8];
  __hip_bfloat16* lb1 = &Bs[c1 * 8];

  for (int k0 = 0; k0 < K; k0 += 32) {
    gl_lds16(a0 + k0, la0);
    gl_lds16(a1 + k0, la1);
    gl_lds16(b0 + k0, lb0);
    gl_lds16(b1 + k0, lb1);
    __syncthreads();
    short8 af[4], bf[4];
#pragma unroll
    for (int i = 0; i < 4; ++i)
      af[i] = *(const short8*)&As[(wr * 64 + i * 16 + r) * 32 + g * 8];
#pragma unroll
    for (int j = 0; j < 4; ++j)
      bf[j] = *(const short8*)&Bs[(wc * 64 + j * 16 + r) * 32 + g * 8];
#pragma unroll
    for (int i = 0; i < 4; ++i)
#pragma unroll
      for (int j = 0; j < 4; ++j) acc[i][j] = MFMA16(af[i], bf[j], acc[i][j]);
    __syncthreads();
  }

#pragma unroll
  for (int i = 0; i < 4; ++i) {
    const int mbase = bm * 128 + wr * 64 + i * 16 + g * 4;
#pragma unroll
    for (int j = 0; j < 4; ++j) {
      const int nn = bn * 128 + wc * 64 + j * 16 + r;
      const float bv = bias[nn];
#pragma unroll
      for (int q = 0; q < 4; ++q)
        outF[(size_t)(mbase + q) * 1024 + nn] = acc[i][j][q] + bv;
    }
  }
}

// ---------------------------------------------------------------- attention v3
// Same mapping as v2 (8 XCD-pinned groups, 8 waves x 16 q-rows). New:
// latency pipelining -- K prefetched 1 tile ahead (double-buffered regs,
// manual 2-unrolled loop), V issued at body top ~500cy before PV use (T14),
// single-compare band mask (uint)(i-j)<=255 removes all edge special-casing.
__global__ __launch_bounds__(512, 4) void attn_local(
    const __hip_bfloat16* __restrict__ qb, const __hip_bfloat16* __restrict__ kb,
    const __hip_bfloat16* __restrict__ vt, __hip_bfloat16* __restrict__ yb) {
  __shared__ alignas(16) __hip_bfloat16 plds[8][16 * 32];
  const int xcd = blockIdx.x & 7, slot = blockIdx.x >> 3;
  const int bh = xcd + (slot >> 4) * 8;  // b*16 + h
  const int qt = slot & 15;
  const int w = threadIdx.x >> 6, lane = threadIdx.x & 63;
  const int r = lane & 15, g = lane >> 4;
  const int qa = qt * 128 + w * 16;

  const __hip_bfloat16* qp = qb + (size_t)bh * 2048 * 64;
  const __hip_bfloat16* kp = kb + (size_t)bh * 2048 * 64;
  const __hip_bfloat16* vp = vt + (size_t)bh * 64 * 2048;

  const short8 qf0 = *(const short8*)&qp[(qa + r) * 64 + g * 8];
  const short8 qf1 = *(const short8*)&qp[(qa + r) * 64 + g * 8 + 32];

  f32x4 acc[4] = {};
  float mrow[4] = {-1e30f, -1e30f, -1e30f, -1e30f};
  float lsum[4] = {0.f, 0.f, 0.f, 0.f};

  const int kb_lo = (qa >= 256) ? ((qa - 255) >> 5) : 0;
  const int kb_hi = (qa + 15) >> 5;

  short8 kA[2][2], kB[2][2], vf[4];

#define LOADK(DST, t_)                                                         \
  do {                                                                         \
    const int kbase_ = (t_) << 5;                                              \
    _Pragma("unroll") for (int f = 0; f < 2; ++f) {                            \
      DST[f][0] = *(const short8*)&kp[(kbase_ + f * 16 + r) * 64 + g * 8];     \
      DST[f][1] = *(const short8*)&kp[(kbase_ + f * 16 + r) * 64 + g * 8 + 32];\
    }                                                                          \
  } while (0)

#define BODY(KS, t_, PREK, KNXT)                                               \
  do {                                                                         \
    const int kbase = (t_) << 5;                                               \
    /* issue V early: use is ~500cy later (after softmax + LDS roundtrip) */   \
    _Pragma("unroll") for (int hdb = 0; hdb < 4; ++hdb)                        \
      vf[hdb] = *(const short8*)&vp[(size_t)(hdb * 16 + r) * 2048 + kbase +    \
                                    g * 8];                                    \
    if (PREK) LOADK(KNXT, (t_) + 1);                                           \
    f32x4 s[2] = {};                                                           \
    _Pragma("unroll") for (int f = 0; f < 2; ++f) {                            \
      s[f] = MFMA16(qf0, KS[f][0], s[f]);                                      \
      s[f] = MFMA16(qf1, KS[f][1], s[f]);                                      \
    }                                                                          \
    float sv[2][4];                                                            \
    _Pragma("unroll") for (int f = 0; f < 2; ++f)                              \
    _Pragma("unroll") for (int q = 0; q < 4; ++q) {                            \
      const unsigned d_ = (unsigned)(qa + g * 4 + q) - (unsigned)(kbase +      \
                                                                  f * 16 + r);\
      sv[f][q] = (d_ <= 255u) ? s[f][q] : -1e30f;                              \
    }                                                                          \
    float tmax = fmaxf(fmaxf(fmaxf(sv[0][0], sv[0][1]),                        \
                             fmaxf(sv[0][2], sv[0][3])),                       \
                       fmaxf(fmaxf(sv[1][0], sv[1][1]),                        \
                             fmaxf(sv[1][2], sv[1][3])));                      \
    float mmin = fminf(fminf(mrow[0], mrow[1]), fminf(mrow[2], mrow[3]));      \
    if (!__all(tmax <= mmin + 8.f)) {                                          \
      float rm[4];                                                             \
      _Pragma("unroll") for (int q = 0; q < 4; ++q)                            \
        rm[q] = fmaxf(sv[0][q], sv[1][q]);                                     \
      _Pragma("unroll") for (int d = 1; d < 16; d <<= 1)                       \
      _Pragma("unroll") for (int q = 0; q < 4; ++q)                            \
        rm[q] = fmaxf(rm[q], __shfl_xor(rm[q], d));                            \
      _Pragma("unroll") for (int q = 0; q < 4; ++q) {                          \
        const float mnew = fmaxf(mrow[q], rm[q]);                              \
        const float fac = __expf(mrow[q] - mnew);                              \
        mrow[q] = mnew;                                                        \
        lsum[q] *= fac;                                                        \
        _Pragma("unroll") for (int hdb = 0; hdb < 4; ++hdb)                    \
          acc[hdb][q] *= fac;                                                  \
      }                                                                        \
    }                                                                          \
    float p[2][4];                                                             \
    _Pragma("unroll") for (int f = 0; f < 2; ++f)                              \
    _Pragma("unroll") for (int q = 0; q < 4; ++q)                              \
      p[f][q] = __expf(sv[f][q] - mrow[q]);                                    \
    _Pragma("unroll") for (int q = 0; q < 4; ++q)                              \
      lsum[q] += p[0][q] + p[1][q];                                            \
    _Pragma("unroll") for (int f = 0; f < 2; ++f)                              \
    _Pragma("unroll") for (int q = 0; q < 4; ++q)                              \
      plds[w][(g * 4 + q) * 32 + f * 16 + r] = __float2bfloat16(p[f][q]);      \
    asm volatile("s_waitcnt lgkmcnt(0)" ::: "memory");                         \
    __builtin_amdgcn_sched_barrier(0);                                         \
    const short8 pa = *(const short8*)&plds[w][r * 32 + g * 8];                \
    _Pragma("unroll") for (int hdb = 0; hdb < 4; ++hdb)                        \
      acc[hdb] = MFMA16(pa, vf[hdb], acc[hdb]);                                \
  } while (0)

  int t = kb_lo;
  LOADK(kA, t);
  while (true) {
    BODY(kA, t, t < kb_hi, kB);
    if (t == kb_hi) break;
    ++t;
    BODY(kB, t, t < kb_hi, kA);
    if (t == kb_hi) break;
    ++t;
  }
#undef BODY
#undef LOADK

  // final l reduction over the 16 key-lanes
#pragma unroll
  for (int d = 1; d < 16; d <<= 1)
#pragma unroll
    for (int q = 0; q < 4; ++q) lsum[q] += __shfl_xor(lsum[q], d);

  const int b_ = bh >> 4, h = bh & 15;
#pragma unroll
  for (int hdb = 0; hdb < 4; ++hdb)
#pragma unroll
    for (int q = 0; q < 4; ++q) {
      const int i_ = qa + g * 4 + q;
      yb[(size_t)(b_ * 2048 + i_) * 1024 + h * 64 + hdb * 16 + r] =
          __float2bfloat16(acc[hdb][q] / lsum[q]);
    }
}

// ---------------------------------------------------------------- launch
extern "C" void kernel_launch(void* const* d_in, const int* in_sizes, int n_in,
                              void* d_out, int out_size, void* d_ws,
                              size_t ws_size, hipStream_t stream) {
  const float* x = (const float*)d_in[0];
  const float* Wqkv = (const float*)d_in[1];
  const float* bqkv = (const float*)d_in[2];
  const float* Wo = (const float*)d_in[3];
  const float* bo = (const float*)d_in[4];
  float* out = (float*)d_out;

  char* ws = (char*)d_ws;
  __hip_bfloat16* xb = (__hip_bfloat16*)(ws + 0);                    // 8 MB
  __hip_bfloat16* wqkvb = (__hip_bfloat16*)(ws + 8388608);           // 6 MB
  __hip_bfloat16* wob = (__hip_bfloat16*)(ws + 14680064);            // 2 MB
  __hip_bfloat16* qb = (__hip_bfloat16*)(ws + 16777216);             // 8 MB
  __hip_bfloat16* kb = (__hip_bfloat16*)(ws + 25165824);             // 8 MB
  __hip_bfloat16* vt = (__hip_bfloat16*)(ws + 33554432);             // 8 MB
  __hip_bfloat16* yb = (__hip_bfloat16*)(ws + 41943040);             // 8 MB

  cvt_all<<<2048, 256, 0, stream>>>(x, Wqkv, Wo, xb, wqkvb, wob);

  // QKV: M=4096, N=3072, K=1024 -> 16x16 = 256 blocks of 256x192
  gemm_qkv<<<256, 512, 0, stream>>>(xb, wqkvb, bqkv, qb, kb, vt);
  // attention: 8 XCD groups x (4 heads x 16 q-tiles of 128)
  attn_local<<<512, 512, 0, stream>>>(qb, kb, vt, yb);
  // out: M=4096, N=1024, K=1024 -> 32x8 = 256 blocks of 128x128
  gemm_bt_out<<<256, 256, 0, stream>>>(yb, wob, bo, out, 1024, 8);
}